// Round 1
// baseline (878.994 us; speedup 1.0000x reference)
//
#include <hip/hip_runtime.h>
#include <stdint.h>

// MHA fused: B=16384, T=32, C=128, H=4, HD=32, fp32 in/out.
// One wave per batch element; bf16 MFMA with 3-term hi/lo split on the Q/K
// path (softmax logits are scaled by sqrt(128) -> need ~fp32 q,k precision).
// All LDS scratch is wave-private -> zero __syncthreads.

typedef __bf16   bf16x8 __attribute__((ext_vector_type(8)));
typedef uint16_t u16x8  __attribute__((ext_vector_type(8)));
typedef float    f32x16 __attribute__((ext_vector_type(16)));

#define T_  32
#define C_  128
#define NH_ 4

// ws element offsets (bf16 units). Fragment arrays are [grp][kk][lane][8]:
// value = W[row=lane&31][col = kk*16 + (lane>>5)*8 + j] of the 32x128 slice.
#define OQHI 0
#define OQLO 16384
#define OKHI 32768
#define OKLO 49152
#define OVHI 65536
#define OWP  81920
// total 98304 bf16 = 196608 bytes of d_ws

__device__ __forceinline__ uint32_t bfbits(float f) {
  // round-to-nearest-even bf16, returned as fp32 bit pattern (low 16 zero)
  uint32_t u = __float_as_uint(f);
  return (u + 0x7FFFu + ((u >> 16) & 1u)) & 0xFFFF0000u;
}

__global__ void prep_weights(const float* __restrict__ Wq, const float* __restrict__ Wk,
                             const float* __restrict__ Wv, const float* __restrict__ Wp,
                             uint16_t* __restrict__ ws) {
  int tid = blockIdx.x * 256 + threadIdx.x;      // 8192 threads
  int sec = tid >> 11;                           // 0=Q 1=K 2=V 3=Wp
  int g   = tid & 2047;                          // (hh, kk, lane)
  int l   = g & 63;
  int kk  = (g >> 6) & 7;
  int hh  = g >> 9;                              // head (or nt for Wp)
  int row  = l & 31;
  int col0 = kk * 16 + (l >> 5) * 8;
  const float* srcs[4] = {Wq, Wk, Wv, Wp};
  // Wq/Wk/Wv: [h][d][c] with HD=32,C=128 -> (hh*32+row)*128+col.
  // Wp: [co][ci] -> (hh*32+row)*128+col. Same formula.
  const float* p = srcs[sec] + (hh * 32 + row) * 128 + col0;
  u16x8 hi, lo;
#pragma unroll
  for (int j = 0; j < 8; j++) {
    float f = p[j];
    uint32_t hb = bfbits(f);
    float lf = f - __uint_as_float(hb);
    hi[j] = (uint16_t)(hb >> 16);
    lo[j] = (uint16_t)(bfbits(lf) >> 16);
  }
  u16x8* w8 = (u16x8*)ws;
  if      (sec == 0) { w8[OQHI / 8 + g] = hi; w8[OQLO / 8 + g] = lo; }
  else if (sec == 1) { w8[OKHI / 8 + g] = hi; w8[OKLO / 8 + g] = lo; }
  else if (sec == 2) { w8[OVHI / 8 + g] = hi; }
  else               { w8[OWP  / 8 + g] = hi; }
}

__device__ __forceinline__ f32x16 mfma_bf16(u16x8 a, u16x8 b, f32x16 c) {
  return __builtin_amdgcn_mfma_f32_32x32x16_bf16(
      __builtin_bit_cast(bf16x8, a), __builtin_bit_cast(bf16x8, b), c, 0, 0, 0);
}

// LDS scratch layout per 32x32 tile: [chunk(4)][row(32)][8 inner] bf16,
// chunk stride padded to 264 elements (528B, 16B-aligned) to spread banks.
#define LCH 264
#define LSZ 1056   // 4*264

__global__ __launch_bounds__(256, 2)
void mha_main(const float* __restrict__ x, const uint16_t* __restrict__ ws,
              const float* __restrict__ bp, float* __restrict__ out) {
  const int lane = threadIdx.x & 63;
  const int wid  = threadIdx.x >> 6;
  const int half = lane >> 5;
  const int rc   = lane & 31;
  const int b    = blockIdx.x * 4 + wid;

  __shared__ __align__(16) uint16_t sm_all[4][6 * LSZ];
  uint16_t* smw  = sm_all[wid];
  uint16_t* qhiL = smw;
  uint16_t* qloL = smw + 1 * LSZ;
  uint16_t* khiL = smw + 2 * LSZ;
  uint16_t* kloL = smw + 3 * LSZ;
  uint16_t* attL = smw + 4 * LSZ;
  uint16_t* vL   = smw + 5 * LSZ;

  const u16x8* w8  = (const u16x8*)ws;
  const u16x8* WQH = w8 + OQHI / 8;
  const u16x8* WQL = w8 + OQLO / 8;
  const u16x8* WKH = w8 + OKHI / 8;
  const u16x8* WKL = w8 + OKLO / 8;
  const u16x8* WVH = w8 + OVHI / 8;
  const u16x8* WPH = w8 + OWP  / 8;

  float bpv[4];
#pragma unroll
  for (int nt = 0; nt < 4; nt++) bpv[nt] = bp[nt * 32 + rc];

  // ---- x as A-fragments, hi/lo split (resident in regs)
  u16x8 xhi[8], xlo[8];
  const float* xb = x + (size_t)b * (T_ * C_) + rc * C_ + half * 8;
#pragma unroll
  for (int kk = 0; kk < 8; kk++) {
    float4 f0 = *(const float4*)(xb + kk * 16);
    float4 f1 = *(const float4*)(xb + kk * 16 + 4);
    float vv[8] = {f0.x, f0.y, f0.z, f0.w, f1.x, f1.y, f1.z, f1.w};
    u16x8 h, l;
#pragma unroll
    for (int j = 0; j < 8; j++) {
      uint32_t hb = bfbits(vv[j]);
      float lf = vv[j] - __uint_as_float(hb);
      h[j] = (uint16_t)(hb >> 16);
      l[j] = (uint16_t)(bfbits(lf) >> 16);
    }
    xhi[kk] = h; xlo[kk] = l;
  }

  f32x16 facc[4] = {};

#pragma unroll 1
  for (int h = 0; h < NH_; h++) {
    // ---- Q = x @ Wq_h^T  (3-term split, 3 independent MFMA chains)
    f32x16 a0 = {}, a1 = {}, a2 = {};
#pragma unroll
    for (int kk = 0; kk < 8; kk++) {
      u16x8 wh = WQH[(h * 8 + kk) * 64 + lane];
      u16x8 wl = WQL[(h * 8 + kk) * 64 + lane];
      a0 = mfma_bf16(xhi[kk], wh, a0);
      a1 = mfma_bf16(xlo[kk], wh, a1);
      a2 = mfma_bf16(xhi[kk], wl, a2);
    }
#pragma unroll
    for (int r = 0; r < 16; r++) {
      float qv = (a0[r] + a1[r]) + a2[r];
      int t = (r & 3) + 8 * (r >> 2) + 4 * half;     // C/D row
      uint32_t hb = bfbits(qv);
      float lf = qv - __uint_as_float(hb);
      int id = (rc >> 3) * LCH + t * 8 + (rc & 7);   // [d-chunk][t][d&7]
      qhiL[id] = (uint16_t)(hb >> 16);
      qloL[id] = (uint16_t)(bfbits(lf) >> 16);
    }
    // ---- K = x @ Wk_h^T
    f32x16 c0 = {}, c1 = {}, c2 = {};
#pragma unroll
    for (int kk = 0; kk < 8; kk++) {
      u16x8 wh = WKH[(h * 8 + kk) * 64 + lane];
      u16x8 wl = WKL[(h * 8 + kk) * 64 + lane];
      c0 = mfma_bf16(xhi[kk], wh, c0);
      c1 = mfma_bf16(xlo[kk], wh, c1);
      c2 = mfma_bf16(xhi[kk], wl, c2);
    }
#pragma unroll
    for (int r = 0; r < 16; r++) {
      float kv = (c0[r] + c1[r]) + c2[r];
      int t = (r & 3) + 8 * (r >> 2) + 4 * half;
      uint32_t hb = bfbits(kv);
      float lf = kv - __uint_as_float(hb);
      int id = (rc >> 3) * LCH + t * 8 + (rc & 7);
      khiL[id] = (uint16_t)(hb >> 16);
      kloL[id] = (uint16_t)(bfbits(lf) >> 16);
    }
    // ---- wei = q @ k^T  (K-dim = HD = 32 -> 2 MFMA steps, 3-term split)
    f32x16 s0 = {}, s1 = {}, s2 = {};
#pragma unroll
    for (int ks = 0; ks < 2; ks++) {
      int off = (ks * 2 + half) * LCH + rc * 8;
      u16x8 qh = *(const u16x8*)(qhiL + off);
      u16x8 ql = *(const u16x8*)(qloL + off);
      u16x8 kh = *(const u16x8*)(khiL + off);
      u16x8 kl = *(const u16x8*)(kloL + off);
      s0 = mfma_bf16(qh, kh, s0);
      s1 = mfma_bf16(ql, kh, s1);
      s2 = mfma_bf16(qh, kl, s2);
    }
    // ---- causal softmax, scale sqrt(C)=sqrt(128). Each row's 32 cols live
    // in one 32-lane half (col = lane&31), so reduce with 5 xor-shuffles.
#pragma unroll
    for (int r = 0; r < 16; r++) {
      int t = (r & 3) + 8 * (r >> 2) + 4 * half;
      int s = rc;
      float logit = ((s0[r] + s1[r]) + s2[r]) * 11.313708498984760390f;
      float mv = (s <= t) ? logit : -3.0e38f;
      mv = fmaxf(mv, __shfl_xor(mv, 1, 64));
      mv = fmaxf(mv, __shfl_xor(mv, 2, 64));
      mv = fmaxf(mv, __shfl_xor(mv, 4, 64));
      mv = fmaxf(mv, __shfl_xor(mv, 8, 64));
      mv = fmaxf(mv, __shfl_xor(mv, 16, 64));
      float pe = (s <= t) ? __expf(logit - mv) : 0.0f;
      float su = pe;
      su += __shfl_xor(su, 1, 64);
      su += __shfl_xor(su, 2, 64);
      su += __shfl_xor(su, 4, 64);
      su += __shfl_xor(su, 8, 64);
      su += __shfl_xor(su, 16, 64);
      float av = pe * __builtin_amdgcn_rcpf(su);
      attL[(s >> 3) * LCH + t * 8 + (s & 7)] = (uint16_t)(bfbits(av) >> 16);
    }
    // ---- V = x @ Wv_h^T  (plain bf16; 2 chains)
    f32x16 v0 = {}, v1 = {};
#pragma unroll
    for (int kk = 0; kk < 8; kk += 2) {
      v0 = mfma_bf16(xhi[kk],     WVH[(h * 8 + kk) * 64 + lane],     v0);
      v1 = mfma_bf16(xhi[kk + 1], WVH[(h * 8 + kk + 1) * 64 + lane], v1);
    }
#pragma unroll
    for (int r = 0; r < 16; r++) {
      float vv = v0[r] + v1[r];
      int s = (r & 3) + 8 * (r >> 2) + 4 * half;     // token index (row of V)
      vL[(s >> 3) * LCH + rc * 8 + (s & 7)] = (uint16_t)(bfbits(vv) >> 16);
    }
    // ---- O_h = att @ v
    f32x16 o = {};
#pragma unroll
    for (int ks = 0; ks < 2; ks++) {
      int off = (ks * 2 + half) * LCH + rc * 8;
      u16x8 af = *(const u16x8*)(attL + off);
      u16x8 vf = *(const u16x8*)(vL + off);
      o = mfma_bf16(af, vf, o);
    }
    // ---- stage O_h in A-layout (reuse qhiL), accumulate out-projection:
    // final[t][co] += sum_d O_h[t][d] * Wp[co][h*32+d]
#pragma unroll
    for (int r = 0; r < 16; r++) {
      int t = (r & 3) + 8 * (r >> 2) + 4 * half;
      qhiL[(rc >> 3) * LCH + t * 8 + (rc & 7)] = (uint16_t)(bfbits(o[r]) >> 16);
    }
#pragma unroll
    for (int kp = 0; kp < 2; kp++) {
      int off = (kp * 2 + half) * LCH + rc * 8;
      u16x8 of = *(const u16x8*)(qhiL + off);
#pragma unroll
      for (int nt = 0; nt < 4; nt++) {
        facc[nt] = mfma_bf16(of, WPH[(nt * 8 + h * 2 + kp) * 64 + lane], facc[nt]);
      }
    }
  }

  // ---- store with bias (lanes 0-31 cover 128B contiguous per reg)
  float* ob = out + (size_t)b * (T_ * C_);
#pragma unroll
  for (int nt = 0; nt < 4; nt++) {
#pragma unroll
    for (int r = 0; r < 16; r++) {
      int t = (r & 3) + 8 * (r >> 2) + 4 * half;
      ob[t * 128 + nt * 32 + rc] = facc[nt][r] + bpv[nt];
    }
  }
}

extern "C" void kernel_launch(void* const* d_in, const int* in_sizes, int n_in,
                              void* d_out, int out_size, void* d_ws, size_t ws_size,
                              hipStream_t stream) {
  const float* x  = (const float*)d_in[0];
  const float* Wq = (const float*)d_in[1];
  const float* Wk = (const float*)d_in[2];
  const float* Wv = (const float*)d_in[3];
  const float* Wp = (const float*)d_in[4];
  const float* bp = (const float*)d_in[5];
  uint16_t* wf = (uint16_t*)d_ws;
  prep_weights<<<32, 256, 0, stream>>>(Wq, Wk, Wv, Wp, wf);
  mha_main<<<4096, 256, 0, stream>>>(x, wf, bp, (float*)d_out);
}

// Round 3
// 754.142 us; speedup vs baseline: 1.1656x; 1.1656x over previous
//
#include <hip/hip_runtime.h>
#include <stdint.h>

// MHA fused: B=16384, T=32, C=128, H=4, HD=32, fp32 in/out.
// One wave per batch element. bf16 MFMA with hi/lo split on the Q/K path.
// R2: S^T softmax (reduction in reg-dim, 2 shuffles/head), b64-packed LDS
// repacks, 2-accumulator split chains, launch_bounds(256,3) for 3 waves/SIMD.
// R3: fix pack_rn2 (no __hip_bfloat162 bit_cast — manual RNE).

typedef __bf16   bf16x8 __attribute__((ext_vector_type(8)));
typedef uint16_t u16x8  __attribute__((ext_vector_type(8)));
typedef uint32_t u32x4  __attribute__((ext_vector_type(4)));
typedef float    f32x16 __attribute__((ext_vector_type(16)));

#define T_  32
#define C_  128
#define NH_ 4

// ws element offsets (bf16 units). Fragment arrays [grp][kk][lane][8]:
// value = W[row=lane&31][col = kk*16 + (lane>>5)*8 + j] of a 32x128 slice.
#define OQHI 0
#define OQLO 16384
#define OKHI 32768
#define OKLO 49152
#define OVHI 65536
#define OWP  81920

__device__ __forceinline__ uint32_t bfbits(float f) {
  // round-to-nearest-even bf16, returned as fp32 bit pattern (low 16 zero)
  uint32_t u = __float_as_uint(f);
  return (u + 0x7FFFu + ((u >> 16) & 1u)) & 0xFFFF0000u;
}

__global__ void prep_weights(const float* __restrict__ Wq, const float* __restrict__ Wk,
                             const float* __restrict__ Wv, const float* __restrict__ Wp,
                             uint16_t* __restrict__ ws) {
  int tid = blockIdx.x * 256 + threadIdx.x;      // 8192 threads
  int sec = tid >> 11;                           // 0=Q 1=K 2=V 3=Wp
  int g   = tid & 2047;
  int l   = g & 63;
  int kk  = (g >> 6) & 7;
  int hh  = g >> 9;
  int row  = l & 31;
  int col0 = kk * 16 + (l >> 5) * 8;
  const float* srcs[4] = {Wq, Wk, Wv, Wp};
  const float* p = srcs[sec] + (hh * 32 + row) * 128 + col0;
  u16x8 hi, lo;
#pragma unroll
  for (int j = 0; j < 8; j++) {
    float f = p[j];
    uint32_t hb = bfbits(f);
    float lf = f - __uint_as_float(hb);
    hi[j] = (uint16_t)(hb >> 16);
    lo[j] = (uint16_t)(bfbits(lf) >> 16);
  }
  u16x8* w8 = (u16x8*)ws;
  if      (sec == 0) { w8[OQHI / 8 + g] = hi; w8[OQLO / 8 + g] = lo; }
  else if (sec == 1) { w8[OKHI / 8 + g] = hi; w8[OKLO / 8 + g] = lo; }
  else if (sec == 2) { w8[OVHI / 8 + g] = hi; }
  else               { w8[OWP  / 8 + g] = hi; }
}

__device__ __forceinline__ f32x16 mfma_bf16(u16x8 a, u16x8 b, f32x16 c) {
  return __builtin_amdgcn_mfma_f32_32x32x16_bf16(
      __builtin_bit_cast(bf16x8, a), __builtin_bit_cast(bf16x8, b), c, 0, 0, 0);
}

// Tile layout: [row 0..31][col 0..31], ST=40 elements, XOR swizzle on col by
// bits of row to kill the rc/rc+8 bank collision. b64 writes (col%4==0) and
// b128 reads (col%8==0) both stay contiguous under the swizzle.
#define ST 40
__device__ __forceinline__ int swz(int row, int col) {
  return row * ST + (col ^ (((row >> 3) & 3) << 3));
}

__device__ __forceinline__ float trunch(float f) {
  return __uint_as_float(__float_as_uint(f) & 0xFFFF0000u);
}
__device__ __forceinline__ uint32_t pack_hi2(float f0, float f1) {
  return (__float_as_uint(f1) & 0xFFFF0000u) | (__float_as_uint(f0) >> 16);
}
__device__ __forceinline__ uint32_t pack_rn2(float f0, float f1) {
  return (bfbits(f1) & 0xFFFF0000u) | (bfbits(f0) >> 16);
}
__device__ __forceinline__ u16x8 rdfrag(const uint16_t* buf, int row, int cb) {
  return *(const u16x8*)(buf + swz(row, cb));
}
__device__ __forceinline__ void write4_rn(uint16_t* buf, int row, int cb,
                                          float f0, float f1, float f2, float f3) {
  uint2 w; w.x = pack_rn2(f0, f1); w.y = pack_rn2(f2, f3);
  *(uint2*)(buf + swz(row, cb)) = w;
}
__device__ __forceinline__ void write4_hilo(uint16_t* bh, uint16_t* bl, int row, int cb,
                                            float f0, float f1, float f2, float f3) {
  uint2 h; h.x = pack_hi2(f0, f1); h.y = pack_hi2(f2, f3);
  *(uint2*)(bh + swz(row, cb)) = h;
  uint2 l; l.x = pack_rn2(f0 - trunch(f0), f1 - trunch(f1));
          l.y = pack_rn2(f2 - trunch(f2), f3 - trunch(f3));
  *(uint2*)(bl + swz(row, cb)) = l;
}

#define SCALE 11.313708498984760390f

__global__ __launch_bounds__(256, 3)
void mha_main(const float* __restrict__ x, const uint16_t* __restrict__ ws,
              const float* __restrict__ bp, float* __restrict__ out) {
  const int lane = threadIdx.x & 63;
  const int wid  = threadIdx.x >> 6;
  const int half = lane >> 5;
  const int rc   = lane & 31;
  const int b    = blockIdx.x * 4 + wid;

  // 4 tile buffers per wave, aliased across phases:
  // B0: qhi -> att   B1: qlo -> O-stage   B2: khi -> v   B3: klo
  __shared__ __align__(16) uint16_t sm[4][4][32 * ST];
  uint16_t* B0 = sm[wid][0];
  uint16_t* B1 = sm[wid][1];
  uint16_t* B2 = sm[wid][2];
  uint16_t* B3 = sm[wid][3];

  const u16x8* w8  = (const u16x8*)ws;
  const u16x8* WQH = w8 + OQHI / 8;
  const u16x8* WQL = w8 + OQLO / 8;
  const u16x8* WKH = w8 + OKHI / 8;
  const u16x8* WKL = w8 + OKLO / 8;
  const u16x8* WVH = w8 + OVHI / 8;
  const u16x8* WPH = w8 + OWP  / 8;

  float bpv[4];
#pragma unroll
  for (int nt = 0; nt < 4; nt++) bpv[nt] = bp[nt * 32 + rc];

  // x as B-fragments [t=lane&31][c], trunc-hi + exact-lo split, in regs.
  u16x8 xhi[8], xlo[8];
  const float* xb = x + (size_t)b * (T_ * C_) + rc * C_ + half * 8;
#pragma unroll
  for (int kk = 0; kk < 8; kk++) {
    float4 f0 = *(const float4*)(xb + kk * 16);
    float4 f1 = *(const float4*)(xb + kk * 16 + 4);
    float vv[8] = {f0.x, f0.y, f0.z, f0.w, f1.x, f1.y, f1.z, f1.w};
    u32x4 hw, lw;
#pragma unroll
    for (int p = 0; p < 4; p++) {
      float a = vv[2 * p], c = vv[2 * p + 1];
      hw[p] = pack_hi2(a, c);
      lw[p] = pack_rn2(a - trunch(a), c - trunch(c));
    }
    xhi[kk] = __builtin_bit_cast(u16x8, hw);
    xlo[kk] = __builtin_bit_cast(u16x8, lw);
  }

  f32x16 facc[4] = {};

#pragma unroll 1
  for (int h = 0; h < NH_; h++) {
    // ---- Q = x@Wq^T, swapped operands: D lane = t, reg = d.
    {
      f32x16 a0 = {}, a1 = {};
#pragma unroll
      for (int kk = 0; kk < 8; kk++) {
        u16x8 wh = WQH[(h * 8 + kk) * 64 + lane];
        u16x8 wl = WQL[(h * 8 + kk) * 64 + lane];
        a0 = mfma_bf16(wh, xhi[kk], a0);
        a1 = mfma_bf16(wl, xhi[kk], a1);
        a1 = mfma_bf16(wh, xlo[kk], a1);
      }
#pragma unroll
      for (int g = 0; g < 4; g++) {
        int cb = 8 * g + 4 * half;
        write4_hilo(B0, B1, rc, cb,
                    a0[4 * g] + a1[4 * g], a0[4 * g + 1] + a1[4 * g + 1],
                    a0[4 * g + 2] + a1[4 * g + 2], a0[4 * g + 3] + a1[4 * g + 3]);
      }
    }
    // ---- K: same shape into B2/B3.
    {
      f32x16 c0 = {}, c1 = {};
#pragma unroll
      for (int kk = 0; kk < 8; kk++) {
        u16x8 wh = WKH[(h * 8 + kk) * 64 + lane];
        u16x8 wl = WKL[(h * 8 + kk) * 64 + lane];
        c0 = mfma_bf16(wh, xhi[kk], c0);
        c1 = mfma_bf16(wl, xhi[kk], c1);
        c1 = mfma_bf16(wh, xlo[kk], c1);
      }
#pragma unroll
      for (int g = 0; g < 4; g++) {
        int cb = 8 * g + 4 * half;
        write4_hilo(B2, B3, rc, cb,
                    c0[4 * g] + c1[4 * g], c0[4 * g + 1] + c1[4 * g + 1],
                    c0[4 * g + 2] + c1[4 * g + 2], c0[4 * g + 3] + c1[4 * g + 3]);
      }
    }
    // ---- S^T = K @ Q^T : D lane = t, reg = s.
    f32x16 s0 = {}, s1 = {};
#pragma unroll
    for (int ks = 0; ks < 2; ks++) {
      int cb = ks * 16 + half * 8;
      u16x8 kh = rdfrag(B2, rc, cb);
      u16x8 kl = rdfrag(B3, rc, cb);
      u16x8 qh = rdfrag(B0, rc, cb);
      u16x8 ql = rdfrag(B1, rc, cb);
      s0 = mfma_bf16(kh, qh, s0);
      s1 = mfma_bf16(kl, qh, s1);
      s1 = mfma_bf16(kh, ql, s1);
    }
    // ---- softmax over s (reg dim); t = rc. 2 shuffles total.
    float mx = -3.0e38f;
#pragma unroll
    for (int r = 0; r < 16; r++) {
      int s = (r & 3) + 8 * (r >> 2) + 4 * half;
      float w = s0[r] + s1[r];
      if (s <= rc) mx = fmaxf(mx, w);
    }
    mx = fmaxf(mx, __shfl_xor(mx, 32, 64));
    float sum = 0.0f;
#pragma unroll
    for (int r = 0; r < 16; r++) {
      int s = (r & 3) + 8 * (r >> 2) + 4 * half;
      if (s <= rc) sum += __expf((s0[r] + s1[r] - mx) * SCALE);
    }
    sum += __shfl_xor(sum, 32, 64);
    float rs = __builtin_amdgcn_rcpf(sum);
    // ---- V = x@Wv^T (unswapped): D lane = d, reg = s.
    f32x16 v0 = {};
#pragma unroll
    for (int kk = 0; kk < 8; kk++)
      v0 = mfma_bf16(xhi[kk], WVH[(h * 8 + kk) * 64 + lane], v0);
    // ---- att -> B0 (row t=rc, cols s), recompute exp; masked lanes write 0.
#pragma unroll
    for (int g = 0; g < 4; g++) {
      int sb = 8 * g + 4 * half;
      float e[4];
#pragma unroll
      for (int i = 0; i < 4; i++) {
        int s = sb + i;
        e[i] = (s <= rc) ? __expf((s0[4 * g + i] + s1[4 * g + i] - mx) * SCALE) * rs : 0.0f;
      }
      write4_rn(B0, rc, sb, e[0], e[1], e[2], e[3]);
    }
    // ---- v -> B2 (row d=rc, cols s).
#pragma unroll
    for (int g = 0; g < 4; g++) {
      int sb = 8 * g + 4 * half;
      write4_rn(B2, rc, sb, v0[4 * g], v0[4 * g + 1], v0[4 * g + 2], v0[4 * g + 3]);
    }
    // ---- O = mfma(A=v[d][s], B=att[t][s]) : D lane = t, reg = d.
    f32x16 o = {};
#pragma unroll
    for (int ks = 0; ks < 2; ks++) {
      int cb = ks * 16 + half * 8;
      u16x8 vf = rdfrag(B2, rc, cb);
      u16x8 af = rdfrag(B0, rc, cb);
      o = mfma_bf16(vf, af, o);
    }
    // ---- O-stage -> B1 (row t=rc, cols d).
#pragma unroll
    for (int g = 0; g < 4; g++) {
      int cb = 8 * g + 4 * half;
      write4_rn(B1, rc, cb, o[4 * g], o[4 * g + 1], o[4 * g + 2], o[4 * g + 3]);
    }
    // ---- out-projection accumulation.
#pragma unroll
    for (int kp = 0; kp < 2; kp++) {
      u16x8 of = rdfrag(B1, rc, kp * 16 + half * 8);
#pragma unroll
      for (int nt = 0; nt < 4; nt++)
        facc[nt] = mfma_bf16(of, WPH[(nt * 8 + h * 2 + kp) * 64 + lane], facc[nt]);
    }
  }

  // ---- store with bias; lanes 0..31 cover 128B contiguous per (nt, r).
  float* ob = out + (size_t)b * (T_ * C_);
#pragma unroll
  for (int nt = 0; nt < 4; nt++) {
#pragma unroll
    for (int r = 0; r < 16; r++) {
      int t = (r & 3) + 8 * (r >> 2) + 4 * half;
      ob[t * 128 + nt * 32 + rc] = facc[nt][r] + bpv[nt];
    }
  }
}

extern "C" void kernel_launch(void* const* d_in, const int* in_sizes, int n_in,
                              void* d_out, int out_size, void* d_ws, size_t ws_size,
                              hipStream_t stream) {
  const float* x  = (const float*)d_in[0];
  const float* Wq = (const float*)d_in[1];
  const float* Wk = (const float*)d_in[2];
  const float* Wv = (const float*)d_in[3];
  const float* Wp = (const float*)d_in[4];
  const float* bp = (const float*)d_in[5];
  uint16_t* wf = (uint16_t*)d_ws;
  prep_weights<<<32, 256, 0, stream>>>(Wq, Wk, Wv, Wp, wf);
  mha_main<<<4096, 256, 0, stream>>>(x, wf, bp, (float*)d_out);
}